// Round 7
// baseline (126.279 us; speedup 1.0000x reference)
//
#include <hip/hip_runtime.h>
#include <hip/hip_fp16.h>

#define VINT 50000
#define NN   10000
#define KK   16
#define DINT 8
#define DEXT 16
#define DD   128
#define BB   2048

typedef __attribute__((ext_vector_type(8))) short  bf16x8;
typedef __attribute__((ext_vector_type(4))) short  short4v;
typedef __attribute__((ext_vector_type(4))) float  f32x4;

struct __align__(8)  half4 { __half2 a, b; };
struct __align__(16) half8 { __half2 a, b, c, d; };

__device__ inline short bf_rne(float f) {
    unsigned u = __float_as_uint(f);
    return (short)((u + 0x7FFFu + ((u >> 16) & 1u)) >> 16);
}

__device__ inline void store_acc(__half* p, f32x4 v) {
    half4 h;
    h.a = __floats2half2_rn(v[0], v[1]);
    h.b = __floats2half2_rn(v[2], v[3]);
    *(half4*)p = h;
}
__device__ inline void store_acc(float* p, f32x4 v) {
    *(float4*)p = make_float4(v[0], v[1], v[2], v[3]);
}

// ---------------------------------------------------------------------------
// Four 128x128 weight mats -> bf16: blocks [0..15]=W,[16..31]=M,[32..47]=U,
// [48..63]=V. W/M stack into WMbf rows 0-255; U/V into UVbf rows 0-255.
// ---------------------------------------------------------------------------
__global__ __launch_bounds__(256) void k_convert_mats(
    const float* __restrict__ W, const float* __restrict__ M,
    const float* __restrict__ U, const float* __restrict__ V,
    short* __restrict__ WMbf, short* __restrict__ UVbf)
{
    int which = blockIdx.x >> 4;
    int i = (blockIdx.x & 15) * 256 + threadIdx.x;   // float4 index, 0..4095
    const float* src = (which == 0) ? W : (which == 1) ? M : (which == 2) ? U : V;
    short* dst = (which < 2) ? WMbf : UVbf;
    int off = (which & 1) * (DD * DD / 4);
    float4 v = ((const float4*)src)[i];
    short4v o = {bf_rne(v.x), bf_rne(v.y), bf_rne(v.z), bf_rne(v.w)};
    ((short4v*)dst)[off + i] = o;
}

// ---------------------------------------------------------------------------
// MFMA dual row-transform: OA[v] = A @ X[v], OB[v] = B @ X[v].
// X is fp32 (converted to bf16 inline; each element consumed exactly once
// grid-wide) or pre-quantized bf16 (InT=short). fp32 accumulate.
// D = AB(256x128) @ X^T(128 x nrows). 256 thr (4 waves), 64 n-cols/block;
// wave w owns m in [64w, 64w+64). No LDS.
// ---------------------------------------------------------------------------
template <typename InT, typename OutT>
__global__ __launch_bounds__(256, 2) void k_mfma_dual(
    const InT* __restrict__ X, const short* __restrict__ ABbf,
    OutT* __restrict__ OA, OutT* __restrict__ OB, int nrows)
{
    const int n0 = blockIdx.x * 64;
    const int w  = threadIdx.x >> 6;
    const int l  = threadIdx.x & 63;
    const int lr = l & 15;
    const int lk = l >> 4;

    f32x4 acc[4][4];
    #pragma unroll
    for (int mi = 0; mi < 4; ++mi)
        #pragma unroll
        for (int ni = 0; ni < 4; ++ni)
            acc[mi][ni] = (f32x4){0.f, 0.f, 0.f, 0.f};

    const bf16x8 zf = {0, 0, 0, 0, 0, 0, 0, 0};

    for (int ks = 0; ks < 4; ++ks) {
        const int kb = ks * 32 + lk * 8;
        bf16x8 ah[4], bh[4];
        #pragma unroll
        for (int mi = 0; mi < 4; ++mi) {
            int m = w * 64 + mi * 16 + lr;
            ah[mi] = *(const bf16x8*)&ABbf[m * DD + kb];
        }
        #pragma unroll
        for (int ni = 0; ni < 4; ++ni) {
            int n = n0 + ni * 16 + lr;
            if (n < nrows) {
                if constexpr (sizeof(InT) == 2) {
                    bh[ni] = *(const bf16x8*)&X[(size_t)n * DD + kb];
                } else {
                    float4 v0 = *(const float4*)&X[(size_t)n * DD + kb];
                    float4 v1 = *(const float4*)&X[(size_t)n * DD + kb + 4];
                    bf16x8 tmp = {bf_rne(v0.x), bf_rne(v0.y), bf_rne(v0.z), bf_rne(v0.w),
                                  bf_rne(v1.x), bf_rne(v1.y), bf_rne(v1.z), bf_rne(v1.w)};
                    bh[ni] = tmp;
                }
            } else bh[ni] = zf;
        }
        #pragma unroll
        for (int mi = 0; mi < 4; ++mi)
            #pragma unroll
            for (int ni = 0; ni < 4; ++ni)
                acc[mi][ni] = __builtin_amdgcn_mfma_f32_16x16x32_bf16(ah[mi], bh[ni], acc[mi][ni], 0, 0, 0);
    }

    // D[m][n]: lane holds col n=tile+lr, rows m=tile+lk*4+r (r=0..3).
    #pragma unroll
    for (int ni = 0; ni < 4; ++ni) {
        int n = n0 + ni * 16 + lr;
        if (n >= nrows) continue;
        #pragma unroll
        for (int mi = 0; mi < 4; ++mi) {
            int m = w * 64 + mi * 16 + lk * 4;
            if (m < DD) store_acc(&OA[(size_t)n * DD + m], acc[mi][ni]);
            else        store_acc(&OB[(size_t)n * DD + (m - DD)], acc[mi][ni]);
        }
    }
}

// ---------------------------------------------------------------------------
// Kernel 2: per node n: r[d] = sum_k relu(WE[nid]+sum_e ME[gid]); h=softmax(r).
// One node per wave-64, 4 k-streams of 16 lanes; lane (stream g16, pos p)
// loads halfs [8p, 8p+8) of each row (16B dwordx4); stream g16 handles
// k = 4*kk + g16. Partials combined with shfl_xor(16|32); softmax over the
// 16-lane group. Output H written as bf16 (feeds the UH/VH MFMA GEMM).
// ---------------------------------------------------------------------------
__global__ __launch_bounds__(256) void k_node(
    const int* __restrict__ node_ids, const int* __restrict__ neigh_ids,
    const __half* __restrict__ WE, const __half* __restrict__ ME,
    short* __restrict__ Hbf)
{
    __shared__ int idx[4][KK * (1 + DINT)];   // per node: [0..15]=nid, [16..143]=gid
    const int t  = threadIdx.x;
    const int n0 = blockIdx.x * 4;

    if (t < 4 * KK) idx[t >> 4][t & 15] = node_ids[n0 * KK + t];
    for (int x = t; x < 4 * KK * DINT; x += 256)
        idx[x >> 7][KK + (x & 127)] = neigh_ids[n0 * KK * DINT + x];
    __syncthreads();

    const int w   = t >> 6;         // node within block
    const int l   = t & 63;
    const int g16 = l >> 4;         // k-stream 0..3
    const int p   = l & 15;         // 16B-chunk position in row
    const int n   = n0 + w;
    const int* ids = idx[w];

    float r[8] = {0.f, 0.f, 0.f, 0.f, 0.f, 0.f, 0.f, 0.f};
    #pragma unroll
    for (int kk = 0; kk < 4; ++kk) {
        const int k = kk * 4 + g16;
        half8 wv = *(const half8*)(WE + (size_t)ids[k] * DD + p * 8);
        float2 f0 = __half22float2(wv.a), f1 = __half22float2(wv.b);
        float2 f2 = __half22float2(wv.c), f3 = __half22float2(wv.d);
        float s[8] = {f0.x, f0.y, f1.x, f1.y, f2.x, f2.y, f3.x, f3.y};
        #pragma unroll
        for (int e = 0; e < DINT; ++e) {
            half8 mv = *(const half8*)(ME + (size_t)ids[KK + k * DINT + e] * DD + p * 8);
            float2 m0 = __half22float2(mv.a), m1 = __half22float2(mv.b);
            float2 m2 = __half22float2(mv.c), m3 = __half22float2(mv.d);
            s[0] += m0.x; s[1] += m0.y; s[2] += m1.x; s[3] += m1.y;
            s[4] += m2.x; s[5] += m2.y; s[6] += m3.x; s[7] += m3.y;
        }
        #pragma unroll
        for (int j = 0; j < 8; ++j) r[j] += fmaxf(s[j], 0.f);
    }

    // combine the 4 k-streams (lanes p, p+16, p+32, p+48 hold same cols)
    #pragma unroll
    for (int j = 0; j < 8; ++j) {
        r[j] += __shfl_xor(r[j], 16);
        r[j] += __shfl_xor(r[j], 32);
    }

    // softmax over 128 cols = 16 lanes x 8 each (all 4 streams identical)
    float mx = r[0];
    #pragma unroll
    for (int j = 1; j < 8; ++j) mx = fmaxf(mx, r[j]);
    #pragma unroll
    for (int off = 8; off >= 1; off >>= 1) mx = fmaxf(mx, __shfl_xor(mx, off));
    float e[8], sum = 0.f;
    #pragma unroll
    for (int j = 0; j < 8; ++j) { e[j] = expf(r[j] - mx); sum += e[j]; }
    #pragma unroll
    for (int off = 8; off >= 1; off >>= 1) sum += __shfl_xor(sum, off);
    float inv = 1.f / sum;
    if (g16 == 0) {
        bf16x8 o = {bf_rne(e[0] * inv), bf_rne(e[1] * inv), bf_rne(e[2] * inv), bf_rne(e[3] * inv),
                    bf_rne(e[4] * inv), bf_rne(e[5] * inv), bf_rne(e[6] * inv), bf_rne(e[7] * inv)};
        *(bf16x8*)(Hbf + (size_t)n * DD + p * 8) = o;
    }
}

// ---------------------------------------------------------------------------
// Kernel 3: e_all[n] = softmax(relu(UH[n] + sum_j VH[ext[n,j]])), fp16 tables.
// One node per wave-64: half hf sums VH rows j=hf*8..hf*8+7 (+UH on hf==0);
// combine with __shfl_xor(.,32).
// ---------------------------------------------------------------------------
__global__ __launch_bounds__(256) void k_ext2(
    const int* __restrict__ ext_neigh, const __half* __restrict__ UH,
    const __half* __restrict__ VH, float* __restrict__ EALL)
{
    __shared__ int idx[4][DEXT];
    const int t  = threadIdx.x;
    const int n0 = blockIdx.x * 4;
    if (t < 4 * DEXT) idx[t >> 4][t & 15] = ext_neigh[n0 * DEXT + t];
    __syncthreads();

    const int w  = t >> 6;
    const int l  = t & 63;
    const int c  = l & 31;
    const int hf = l >> 5;
    const int n  = n0 + w;

    float sx = 0.f, sy = 0.f, sz = 0.f, sw = 0.f;
    if (hf == 0) {
        half4 a = *(const half4*)(UH + (size_t)n * DD + 4 * c);
        float2 a0 = __half22float2(a.a), a1 = __half22float2(a.b);
        sx = a0.x; sy = a0.y; sz = a1.x; sw = a1.y;
    }
    #pragma unroll
    for (int jj = 0; jj < 8; ++jj) {
        half4 v = *(const half4*)(VH + (size_t)idx[w][hf * 8 + jj] * DD + 4 * c);
        float2 v0 = __half22float2(v.a), v1 = __half22float2(v.b);
        sx += v0.x; sy += v0.y; sz += v1.x; sw += v1.y;
    }
    sx += __shfl_xor(sx, 32); sy += __shfl_xor(sy, 32);
    sz += __shfl_xor(sz, 32); sw += __shfl_xor(sw, 32);

    sx = fmaxf(sx, 0.f); sy = fmaxf(sy, 0.f);
    sz = fmaxf(sz, 0.f); sw = fmaxf(sw, 0.f);

    float mx = fmaxf(fmaxf(sx, sy), fmaxf(sz, sw));
    #pragma unroll
    for (int off = 16; off >= 1; off >>= 1) mx = fmaxf(mx, __shfl_xor(mx, off));
    float ex = expf(sx - mx), ey = expf(sy - mx), ez = expf(sz - mx), ew = expf(sw - mx);
    float s = ex + ey + ez + ew;
    #pragma unroll
    for (int off = 16; off >= 1; off >>= 1) s += __shfl_xor(s, off);
    float inv = 1.f / s;
    if (hf == 0)
        *(float4*)(EALL + (size_t)n * DD + 4 * c) = make_float4(ex * inv, ey * inv, ez * inv, ew * inv);
}

// ---------------------------------------------------------------------------
// Kernel 4: per batch pair: 2-layer MLP head + softmax(2)
// ---------------------------------------------------------------------------
__global__ __launch_bounds__(128) void k_mlp(
    const int* __restrict__ batch, const float* __restrict__ EALL,
    const float* __restrict__ W1, const float* __restrict__ b1,
    const float* __restrict__ W2, const float* __restrict__ b2,
    float* __restrict__ out)
{
    const int b = blockIdx.x;
    const int t = threadIdx.x;
    __shared__ float cat[2 * DD];
    const int ia = batch[2 * b];
    const int ib = batch[2 * b + 1];
    cat[t]      = EALL[(size_t)ia * DD + t];
    cat[DD + t] = EALL[(size_t)ib * DD + t];
    __syncthreads();

    float x = b1[t];
    const float* w1r = W1 + t * (2 * DD);
    for (int j = 0; j < 2 * DD; ++j) x = fmaf(w1r[j], cat[j], x);
    x = (x > 0.f) ? x : 0.01f * x;

    float p0 = W2[t] * x;
    float p1 = W2[DD + t] * x;
    __shared__ float red[4];
    #pragma unroll
    for (int off = 32; off >= 1; off >>= 1) {
        p0 += __shfl_xor(p0, off);
        p1 += __shfl_xor(p1, off);
    }
    if ((t & 63) == 0) { red[t >> 6] = p0; red[2 + (t >> 6)] = p1; }
    __syncthreads();
    if (t == 0) {
        float l0 = red[0] + red[1] + b2[0];
        float l1 = red[2] + red[3] + b2[1];
        float mm = fmaxf(l0, l1);
        float e0 = expf(l0 - mm), e1 = expf(l1 - mm);
        float inv = 1.f / (e0 + e1);
        out[2 * b]     = e0 * inv;
        out[2 * b + 1] = e1 * inv;
    }
}

// ---------------------------------------------------------------------------
extern "C" void kernel_launch(void* const* d_in, const int* in_sizes, int n_in,
                              void* d_out, int out_size, void* d_ws, size_t ws_size,
                              hipStream_t stream) {
    const int*   batch     = (const int*)d_in[0];
    const int*   node_ids  = (const int*)d_in[1];
    const int*   neigh_ids = (const int*)d_in[2];
    const int*   ext_neigh = (const int*)d_in[3];
    const float* E         = (const float*)d_in[4];
    const float* W         = (const float*)d_in[5];
    const float* M         = (const float*)d_in[6];
    const float* U         = (const float*)d_in[7];
    const float* V         = (const float*)d_in[8];
    const float* W1        = (const float*)d_in[9];
    const float* b1        = (const float*)d_in[10];
    const float* W2        = (const float*)d_in[11];
    const float* b2        = (const float*)d_in[12];

    // workspace layout (~38.6 MB, all 16B-aligned)
    __half* WE   = (__half*)d_ws;                    // 12.8 MB
    __half* ME   = WE + (size_t)VINT * DD;           // 12.8 MB
    short*  Hbf  = (short*)(ME + (size_t)VINT * DD); // 2.56 MB
    short*  WMbf = Hbf + (size_t)NN * DD;            // 64 KB
    short*  UVbf = WMbf + 256 * DD;                  // 64 KB
    __half* UHh  = (__half*)(UVbf + 256 * DD);       // 2.56 MB
    __half* VHh  = UHh + (size_t)NN * DD;            // 2.56 MB
    float*  EA   = (float*)(VHh + (size_t)NN * DD);  // 5.12 MB
    float*  out  = (float*)d_out;

    k_convert_mats<<<64, 256, 0, stream>>>(W, M, U, V, WMbf, UVbf);
    k_mfma_dual<float, __half><<<(VINT + 63) / 64, 256, 0, stream>>>(E, WMbf, WE, ME, VINT);
    k_node<<<NN / 4, 256, 0, stream>>>(node_ids, neigh_ids, WE, ME, Hbf);
    k_mfma_dual<short, __half><<<(NN + 63) / 64, 256, 0, stream>>>(Hbf, UVbf, UHh, VHh, NN);
    k_ext2<<<NN / 4, 256, 0, stream>>>(ext_neigh, UHh, VHh, EA);
    k_mlp<<<BB, 128, 0, stream>>>(batch, EA, W1, b1, W2, b2, out);
}

// Round 8
// 105.413 us; speedup vs baseline: 1.1979x; 1.1979x over previous
//
#include <hip/hip_runtime.h>
#include <hip/hip_fp16.h>

#define VINT 50000
#define NN   10000
#define KK   16
#define DINT 8
#define DEXT 16
#define DD   128
#define BB   2048

typedef __attribute__((ext_vector_type(8))) short  bf16x8;
typedef __attribute__((ext_vector_type(4))) short  short4v;
typedef __attribute__((ext_vector_type(4))) float  f32x4;

struct __align__(8)  half4 { __half2 a, b; };
struct __align__(16) half8 { __half2 a, b, c, d; };

__device__ inline short bf_rne(float f) {
    unsigned u = __float_as_uint(f);
    return (short)((u + 0x7FFFu + ((u >> 16) & 1u)) >> 16);
}

__device__ inline void store_acc(__half* p, f32x4 v) {
    half4 h;
    h.a = __floats2half2_rn(v[0], v[1]);
    h.b = __floats2half2_rn(v[2], v[3]);
    *(half4*)p = h;
}
__device__ inline void store_acc(float* p, f32x4 v) {
    *(float4*)p = make_float4(v[0], v[1], v[2], v[3]);
}

// ---------------------------------------------------------------------------
// fp32 -> bf16 (RNE) bulk convert, float4/thread.
// ---------------------------------------------------------------------------
__global__ __launch_bounds__(256) void k_convert(
    const float* __restrict__ src, short* __restrict__ dst, int n4)
{
    int i = blockIdx.x * 256 + threadIdx.x;
    if (i >= n4) return;
    float4 v = ((const float4*)src)[i];
    short4v o = {bf_rne(v.x), bf_rne(v.y), bf_rne(v.z), bf_rne(v.w)};
    ((short4v*)dst)[i] = o;
}

// ---------------------------------------------------------------------------
// Weight mats -> bf16. Blocks [0..15]=W,[16..31]=M,[32..47]=U,[48..63]=V,
// [64..95]=W1 (128x256). W/M stack into WMbf rows 0-255; U/V into UVbf.
// ---------------------------------------------------------------------------
__global__ __launch_bounds__(256) void k_convert_mats(
    const float* __restrict__ W, const float* __restrict__ M,
    const float* __restrict__ U, const float* __restrict__ V,
    const float* __restrict__ W1,
    short* __restrict__ WMbf, short* __restrict__ UVbf,
    short* __restrict__ W1bf)
{
    int bid = blockIdx.x;
    if (bid < 64) {
        int which = bid >> 4;
        int i = (bid & 15) * 256 + threadIdx.x;   // float4 index, 0..4095
        const float* src = (which == 0) ? W : (which == 1) ? M : (which == 2) ? U : V;
        short* dst = (which < 2) ? WMbf : UVbf;
        int off = (which & 1) * (DD * DD / 4);
        float4 v = ((const float4*)src)[i];
        short4v o = {bf_rne(v.x), bf_rne(v.y), bf_rne(v.z), bf_rne(v.w)};
        ((short4v*)dst)[off + i] = o;
    } else {
        int i = (bid - 64) * 256 + threadIdx.x;   // float4 index, 0..8191
        float4 v = ((const float4*)W1)[i];
        short4v o = {bf_rne(v.x), bf_rne(v.y), bf_rne(v.z), bf_rne(v.w)};
        ((short4v*)W1bf)[i] = o;
    }
}

// ---------------------------------------------------------------------------
// MFMA dual row-transform: OA[v] = A @ X[v], OB[v] = B @ X[v], bf16 inputs,
// fp32 accumulate. D = AB(256x128) @ X^T(128 x nrows). 256 thr (4 waves),
// 64 n-cols/block; wave w owns m in [64w, 64w+64). No LDS.
// ---------------------------------------------------------------------------
template <typename OutT>
__global__ __launch_bounds__(256, 2) void k_mfma_dual(
    const short* __restrict__ Xbf, const short* __restrict__ ABbf,
    OutT* __restrict__ OA, OutT* __restrict__ OB, int nrows)
{
    const int n0 = blockIdx.x * 64;
    const int w  = threadIdx.x >> 6;
    const int l  = threadIdx.x & 63;
    const int lr = l & 15;
    const int lk = l >> 4;

    f32x4 acc[4][4];
    #pragma unroll
    for (int mi = 0; mi < 4; ++mi)
        #pragma unroll
        for (int ni = 0; ni < 4; ++ni)
            acc[mi][ni] = (f32x4){0.f, 0.f, 0.f, 0.f};

    const bf16x8 zf = {0, 0, 0, 0, 0, 0, 0, 0};

    for (int ks = 0; ks < 4; ++ks) {
        const int kb = ks * 32 + lk * 8;
        bf16x8 ah[4], bh[4];
        #pragma unroll
        for (int mi = 0; mi < 4; ++mi) {
            int m = w * 64 + mi * 16 + lr;
            ah[mi] = *(const bf16x8*)&ABbf[m * DD + kb];
        }
        #pragma unroll
        for (int ni = 0; ni < 4; ++ni) {
            int n = n0 + ni * 16 + lr;
            bh[ni] = (n < nrows) ? *(const bf16x8*)&Xbf[(size_t)n * DD + kb] : zf;
        }
        #pragma unroll
        for (int mi = 0; mi < 4; ++mi)
            #pragma unroll
            for (int ni = 0; ni < 4; ++ni)
                acc[mi][ni] = __builtin_amdgcn_mfma_f32_16x16x32_bf16(ah[mi], bh[ni], acc[mi][ni], 0, 0, 0);
    }

    // D[m][n]: lane holds col n=tile+lr, rows m=tile+lk*4+r (r=0..3).
    #pragma unroll
    for (int ni = 0; ni < 4; ++ni) {
        int n = n0 + ni * 16 + lr;
        if (n >= nrows) continue;
        #pragma unroll
        for (int mi = 0; mi < 4; ++mi) {
            int m = w * 64 + mi * 16 + lk * 4;
            if (m < DD) store_acc(&OA[(size_t)n * DD + m], acc[mi][ni]);
            else        store_acc(&OB[(size_t)n * DD + (m - DD)], acc[mi][ni]);
        }
    }
}

// ---------------------------------------------------------------------------
// Kernel 2: per node n: r[d] = sum_k relu(WE[nid]+sum_e ME[gid]); h=softmax(r).
// One node per wave-64, 4 k-streams of 16 lanes; lane (stream g16, pos p)
// loads halfs [8p, 8p+8) (16B). All 9 row-loads of a k are register-batched
// (issued before any use) to maximize loads in flight; launch_bounds(256,7)
// gives the allocator ~73 VGPR. Partials combined via shfl_xor(16|32);
// softmax over the 16-lane group; H written as bf16.
// ---------------------------------------------------------------------------
__global__ __launch_bounds__(256, 7) void k_node(
    const int* __restrict__ node_ids, const int* __restrict__ neigh_ids,
    const __half* __restrict__ WE, const __half* __restrict__ ME,
    short* __restrict__ Hbf)
{
    __shared__ int idx[4][KK * (1 + DINT)];   // per node: [0..15]=nid, [16..143]=gid
    const int t  = threadIdx.x;
    const int n0 = blockIdx.x * 4;

    if (t < 4 * KK) idx[t >> 4][t & 15] = node_ids[n0 * KK + t];
    for (int x = t; x < 4 * KK * DINT; x += 256)
        idx[x >> 7][KK + (x & 127)] = neigh_ids[n0 * KK * DINT + x];
    __syncthreads();

    const int w   = t >> 6;         // node within block
    const int l   = t & 63;
    const int g16 = l >> 4;         // k-stream 0..3
    const int p   = l & 15;         // 16B-chunk position in row
    const int n   = n0 + w;
    const int* ids = idx[w];

    float r[8] = {0.f, 0.f, 0.f, 0.f, 0.f, 0.f, 0.f, 0.f};
    #pragma unroll
    for (int kk = 0; kk < 4; ++kk) {
        const int k = kk * 4 + g16;
        // batch-issue all 9 loads for this k before any conversion
        half8 rw = *(const half8*)(WE + (size_t)ids[k] * DD + p * 8);
        half8 rm[DINT];
        #pragma unroll
        for (int e = 0; e < DINT; ++e)
            rm[e] = *(const half8*)(ME + (size_t)ids[KK + k * DINT + e] * DD + p * 8);

        float2 f0 = __half22float2(rw.a), f1 = __half22float2(rw.b);
        float2 f2 = __half22float2(rw.c), f3 = __half22float2(rw.d);
        float s[8] = {f0.x, f0.y, f1.x, f1.y, f2.x, f2.y, f3.x, f3.y};
        #pragma unroll
        for (int e = 0; e < DINT; ++e) {
            float2 m0 = __half22float2(rm[e].a), m1 = __half22float2(rm[e].b);
            float2 m2 = __half22float2(rm[e].c), m3 = __half22float2(rm[e].d);
            s[0] += m0.x; s[1] += m0.y; s[2] += m1.x; s[3] += m1.y;
            s[4] += m2.x; s[5] += m2.y; s[6] += m3.x; s[7] += m3.y;
        }
        #pragma unroll
        for (int j = 0; j < 8; ++j) r[j] += fmaxf(s[j], 0.f);
    }

    // combine the 4 k-streams (lanes p, p+16, p+32, p+48 hold same cols)
    #pragma unroll
    for (int j = 0; j < 8; ++j) {
        r[j] += __shfl_xor(r[j], 16);
        r[j] += __shfl_xor(r[j], 32);
    }

    // softmax over 128 cols = 16 lanes x 8 each (all 4 streams identical)
    float mx = r[0];
    #pragma unroll
    for (int j = 1; j < 8; ++j) mx = fmaxf(mx, r[j]);
    #pragma unroll
    for (int off = 8; off >= 1; off >>= 1) mx = fmaxf(mx, __shfl_xor(mx, off));
    float e[8], sum = 0.f;
    #pragma unroll
    for (int j = 0; j < 8; ++j) { e[j] = expf(r[j] - mx); sum += e[j]; }
    #pragma unroll
    for (int off = 8; off >= 1; off >>= 1) sum += __shfl_xor(sum, off);
    float inv = 1.f / sum;
    if (g16 == 0) {
        bf16x8 o = {bf_rne(e[0] * inv), bf_rne(e[1] * inv), bf_rne(e[2] * inv), bf_rne(e[3] * inv),
                    bf_rne(e[4] * inv), bf_rne(e[5] * inv), bf_rne(e[6] * inv), bf_rne(e[7] * inv)};
        *(bf16x8*)(Hbf + (size_t)n * DD + p * 8) = o;
    }
}

// ---------------------------------------------------------------------------
// Kernel 3: e_all[n] = softmax(relu(UH[n] + sum_j VH[ext[n,j]])), fp16 tables.
// One node per wave-64: half hf sums VH rows j=hf*8..hf*8+7 (+UH on hf==0).
// ---------------------------------------------------------------------------
__global__ __launch_bounds__(256) void k_ext2(
    const int* __restrict__ ext_neigh, const __half* __restrict__ UH,
    const __half* __restrict__ VH, float* __restrict__ EALL)
{
    __shared__ int idx[4][DEXT];
    const int t  = threadIdx.x;
    const int n0 = blockIdx.x * 4;
    if (t < 4 * DEXT) idx[t >> 4][t & 15] = ext_neigh[n0 * DEXT + t];
    __syncthreads();

    const int w  = t >> 6;
    const int l  = t & 63;
    const int c  = l & 31;
    const int hf = l >> 5;
    const int n  = n0 + w;

    float sx = 0.f, sy = 0.f, sz = 0.f, sw = 0.f;
    if (hf == 0) {
        half4 a = *(const half4*)(UH + (size_t)n * DD + 4 * c);
        float2 a0 = __half22float2(a.a), a1 = __half22float2(a.b);
        sx = a0.x; sy = a0.y; sz = a1.x; sw = a1.y;
    }
    #pragma unroll
    for (int jj = 0; jj < 8; ++jj) {
        half4 v = *(const half4*)(VH + (size_t)idx[w][hf * 8 + jj] * DD + 4 * c);
        float2 v0 = __half22float2(v.a), v1 = __half22float2(v.b);
        sx += v0.x; sy += v0.y; sz += v1.x; sw += v1.y;
    }
    sx += __shfl_xor(sx, 32); sy += __shfl_xor(sy, 32);
    sz += __shfl_xor(sz, 32); sw += __shfl_xor(sw, 32);

    sx = fmaxf(sx, 0.f); sy = fmaxf(sy, 0.f);
    sz = fmaxf(sz, 0.f); sw = fmaxf(sw, 0.f);

    float mx = fmaxf(fmaxf(sx, sy), fmaxf(sz, sw));
    #pragma unroll
    for (int off = 16; off >= 1; off >>= 1) mx = fmaxf(mx, __shfl_xor(mx, off));
    float ex = expf(sx - mx), ey = expf(sy - mx), ez = expf(sz - mx), ew = expf(sw - mx);
    float s = ex + ey + ez + ew;
    #pragma unroll
    for (int off = 16; off >= 1; off >>= 1) s += __shfl_xor(s, off);
    float inv = 1.f / s;
    if (hf == 0)
        *(float4*)(EALL + (size_t)n * DD + 4 * c) = make_float4(ex * inv, ey * inv, ez * inv, ew * inv);
}

// ---------------------------------------------------------------------------
// Kernel 4 (MFMA): 64 batch pairs per block.
// X = leaky(W1 @ cat^T + b1): D(m=128, n=64 pairs), K=256.
// cat row n = [EA[ia]; EA[ib]] converted to bf16 at load.
// Epilogue: logits = W2 @ X + b2, softmax-2.
// ---------------------------------------------------------------------------
__global__ __launch_bounds__(256) void k_mlp_mfma(
    const int* __restrict__ batch, const float* __restrict__ EA,
    const short* __restrict__ W1bf, const float* __restrict__ b1,
    const float* __restrict__ W2, const float* __restrict__ b2,
    float* __restrict__ out)
{
    __shared__ int pidx[128];
    __shared__ float red0[4][64];
    __shared__ float red1[4][64];
    const int t = threadIdx.x, w = t >> 6, l = t & 63;
    const int lr = l & 15, lk = l >> 4;
    const int b0 = blockIdx.x * 64;

    if (t < 128) pidx[t] = batch[b0 * 2 + t];
    __syncthreads();

    f32x4 acc[2][4];
    #pragma unroll
    for (int mi = 0; mi < 2; ++mi)
        #pragma unroll
        for (int ni = 0; ni < 4; ++ni)
            acc[mi][ni] = (f32x4){0.f, 0.f, 0.f, 0.f};

    for (int ks = 0; ks < 8; ++ks) {
        const int kb = ks * 32 + lk * 8;
        const int sel = (ks >= 4);          // second half of concat
        const int koff = kb - sel * 128;
        bf16x8 ah[2], bh[4];
        #pragma unroll
        for (int mi = 0; mi < 2; ++mi) {
            int m = w * 32 + mi * 16 + lr;
            ah[mi] = *(const bf16x8*)&W1bf[m * (2 * DD) + kb];
        }
        #pragma unroll
        for (int ni = 0; ni < 4; ++ni) {
            int n = ni * 16 + lr;
            int row = pidx[2 * n + sel];
            float4 v0 = *(const float4*)&EA[(size_t)row * DD + koff];
            float4 v1 = *(const float4*)&EA[(size_t)row * DD + koff + 4];
            bf16x8 tmp = {bf_rne(v0.x), bf_rne(v0.y), bf_rne(v0.z), bf_rne(v0.w),
                          bf_rne(v1.x), bf_rne(v1.y), bf_rne(v1.z), bf_rne(v1.w)};
            bh[ni] = tmp;
        }
        #pragma unroll
        for (int mi = 0; mi < 2; ++mi)
            #pragma unroll
            for (int ni = 0; ni < 4; ++ni)
                acc[mi][ni] = __builtin_amdgcn_mfma_f32_16x16x32_bf16(ah[mi], bh[ni], acc[mi][ni], 0, 0, 0);
    }

    // hoist b1/W2 (m depends only on mi,r for this lane)
    float bb[2][4], w2a[2][4], w2b[2][4];
    #pragma unroll
    for (int mi = 0; mi < 2; ++mi)
        #pragma unroll
        for (int rr = 0; rr < 4; ++rr) {
            int m = w * 32 + mi * 16 + lk * 4 + rr;
            bb[mi][rr]  = b1[m];
            w2a[mi][rr] = W2[m];
            w2b[mi][rr] = W2[DD + m];
        }

    #pragma unroll
    for (int ni = 0; ni < 4; ++ni) {
        float p0 = 0.f, p1 = 0.f;
        #pragma unroll
        for (int mi = 0; mi < 2; ++mi)
            #pragma unroll
            for (int rr = 0; rr < 4; ++rr) {
                float x = acc[mi][ni][rr] + bb[mi][rr];
                x = (x > 0.f) ? x : 0.01f * x;
                p0 = fmaf(w2a[mi][rr], x, p0);
                p1 = fmaf(w2b[mi][rr], x, p1);
            }
        p0 += __shfl_xor(p0, 16); p0 += __shfl_xor(p0, 32);
        p1 += __shfl_xor(p1, 16); p1 += __shfl_xor(p1, 32);
        if (lk == 0) {
            red0[w][ni * 16 + lr] = p0;
            red1[w][ni * 16 + lr] = p1;
        }
    }
    __syncthreads();
    if (t < 64) {
        float l0 = red0[0][t] + red0[1][t] + red0[2][t] + red0[3][t] + b2[0];
        float l1 = red1[0][t] + red1[1][t] + red1[2][t] + red1[3][t] + b2[1];
        float mm = fmaxf(l0, l1);
        float e0 = expf(l0 - mm), e1 = expf(l1 - mm);
        float inv = 1.f / (e0 + e1);
        out[2 * (b0 + t)]     = e0 * inv;
        out[2 * (b0 + t) + 1] = e1 * inv;
    }
}

// ---------------------------------------------------------------------------
extern "C" void kernel_launch(void* const* d_in, const int* in_sizes, int n_in,
                              void* d_out, int out_size, void* d_ws, size_t ws_size,
                              hipStream_t stream) {
    const int*   batch     = (const int*)d_in[0];
    const int*   node_ids  = (const int*)d_in[1];
    const int*   neigh_ids = (const int*)d_in[2];
    const int*   ext_neigh = (const int*)d_in[3];
    const float* E         = (const float*)d_in[4];
    const float* W         = (const float*)d_in[5];
    const float* M         = (const float*)d_in[6];
    const float* U         = (const float*)d_in[7];
    const float* V         = (const float*)d_in[8];
    const float* W1        = (const float*)d_in[9];
    const float* b1        = (const float*)d_in[10];
    const float* W2        = (const float*)d_in[11];
    const float* b2        = (const float*)d_in[12];

    // workspace layout (~51.5 MB, all 16B-aligned)
    __half* WE   = (__half*)d_ws;                    // 12.8 MB
    __half* ME   = WE + (size_t)VINT * DD;           // 12.8 MB
    short*  Ebf  = (short*)(ME + (size_t)VINT * DD); // 12.8 MB
    short*  Hbf  = Ebf + (size_t)VINT * DD;          // 2.56 MB
    short*  WMbf = Hbf + (size_t)NN * DD;            // 64 KB
    short*  UVbf = WMbf + 256 * DD;                  // 64 KB
    short*  W1bf = UVbf + 256 * DD;                  // 64 KB
    __half* UHh  = (__half*)(W1bf + DD * 2 * DD);    // 2.56 MB
    __half* VHh  = UHh + (size_t)NN * DD;            // 2.56 MB
    float*  EA   = (float*)(VHh + (size_t)NN * DD);  // 5.12 MB
    float*  out  = (float*)d_out;

    k_convert<<<(VINT * DD / 4 + 255) / 256, 256, 0, stream>>>(E, Ebf, VINT * DD / 4);
    k_convert_mats<<<96, 256, 0, stream>>>(W, M, U, V, W1, WMbf, UVbf, W1bf);
    k_mfma_dual<__half><<<(VINT + 63) / 64, 256, 0, stream>>>(Ebf, WMbf, WE, ME, VINT);
    k_node<<<NN / 4, 256, 0, stream>>>(node_ids, neigh_ids, WE, ME, Hbf);
    k_mfma_dual<__half><<<(NN + 63) / 64, 256, 0, stream>>>(Hbf, UVbf, UHh, VHh, NN);
    k_ext2<<<NN / 4, 256, 0, stream>>>(ext_neigh, UHh, VHh, EA);
    k_mlp_mfma<<<BB / 64, 256, 0, stream>>>(batch, EA, W1bf, b1, W2, b2, out);
}